// Round 1
// baseline (11038.141 us; speedup 1.0000x reference)
//
#include <hip/hip_runtime.h>

#define N_NODES 100000
#define N_EDGES 3200000
#define DIM 256

// ---------------------------------------------------------------------------
// GEMM: support[M, 256] = x[M, 256] @ W[256, 256], fp32, LDS-tiled.
// BM=64, BN=64, BK=16, 256 threads, 4x4 micro-tile per thread.
// ---------------------------------------------------------------------------
__global__ __launch_bounds__(256) void gemm_kernel(const float* __restrict__ A,
                                                   const float* __restrict__ B,
                                                   float* __restrict__ C, int M) {
    __shared__ float As[16][64 + 1];  // [k][m], +1 pad
    __shared__ float Bs[16][64 + 1];  // [k][n]

    const int row0 = blockIdx.x * 64;
    const int col0 = blockIdx.y * 64;
    const int tid = threadIdx.x;
    const int tx = tid & 15;   // n-dir, 16 threads
    const int ty = tid >> 4;   // m-dir, 16 threads

    float acc[4][4] = {};

    for (int k0 = 0; k0 < DIM; k0 += 16) {
        // Load A tile 64x16 (1024 elems, 4/thread). Store transposed As[k][m].
#pragma unroll
        for (int i = 0; i < 4; i++) {
            int idx = tid + i * 256;
            int r = idx >> 4, c = idx & 15;
            int gr = row0 + r;
            As[c][r] = (gr < M) ? A[(size_t)gr * DIM + k0 + c] : 0.f;
        }
        // Load B tile 16x64 (1024 elems, 4/thread). Bs[k][n].
#pragma unroll
        for (int i = 0; i < 4; i++) {
            int idx = tid + i * 256;
            int r = idx >> 6, c = idx & 63;
            Bs[r][c] = B[(size_t)(k0 + r) * DIM + col0 + c];
        }
        __syncthreads();

#pragma unroll
        for (int k = 0; k < 16; k++) {
            float a[4], b[4];
#pragma unroll
            for (int i = 0; i < 4; i++) a[i] = As[k][ty * 4 + i];
#pragma unroll
            for (int j = 0; j < 4; j++) b[j] = Bs[k][tx * 4 + j];
#pragma unroll
            for (int i = 0; i < 4; i++)
#pragma unroll
                for (int j = 0; j < 4; j++) acc[i][j] += a[i] * b[j];
        }
        __syncthreads();
    }

#pragma unroll
    for (int i = 0; i < 4; i++) {
        int gr = row0 + ty * 4 + i;
        if (gr < M) {
            float4 v = make_float4(acc[i][0], acc[i][1], acc[i][2], acc[i][3]);
            *(float4*)(C + (size_t)gr * DIM + col0 + tx * 4) = v;
        }
    }
}

// ---------------------------------------------------------------------------
// Scatter SpMM: one wave (64 lanes) per edge; float4 per lane covers 256 dims.
// out[row] += val * support[col]   (atomicAdd, rows collide across edges)
// ---------------------------------------------------------------------------
__global__ __launch_bounds__(256) void scatter_kernel(const float* __restrict__ support,
                                                      const int* __restrict__ erow,
                                                      const int* __restrict__ ecol,
                                                      const float* __restrict__ eval,
                                                      float* __restrict__ out, int nE) {
    int wid = (blockIdx.x * blockDim.x + threadIdx.x) >> 6;
    int lane = threadIdx.x & 63;
    if (wid >= nE) return;

    int r = erow[wid];
    int c = ecol[wid];
    float v = eval[wid];

    const float4* src = (const float4*)(support + (size_t)c * DIM);
    float4 s = src[lane];
    float* dst = out + (size_t)r * DIM + lane * 4;
    atomicAdd(dst + 0, v * s.x);
    atomicAdd(dst + 1, v * s.y);
    atomicAdd(dst + 2, v * s.z);
    atomicAdd(dst + 3, v * s.w);
}

extern "C" void kernel_launch(void* const* d_in, const int* in_sizes, int n_in,
                              void* d_out, int out_size, void* d_ws, size_t ws_size,
                              hipStream_t stream) {
    const float* x    = (const float*)d_in[0];
    const float* w    = (const float*)d_in[1];
    const int*   erow = (const int*)d_in[2];
    const int*   ecol = (const int*)d_in[3];
    const float* eval = (const float*)d_in[4];
    float* out = (float*)d_out;
    float* support = (float*)d_ws;  // 100000*256*4 = 102.4 MB

    // Zero the (0xAA-poisoned) output.
    hipMemsetAsync(d_out, 0, (size_t)N_NODES * DIM * sizeof(float), stream);

    // support = x @ W
    dim3 grid((N_NODES + 63) / 64, DIM / 64);
    gemm_kernel<<<grid, 256, 0, stream>>>(x, w, support, N_NODES);

    // out[r] += v * support[c], one wave per edge, 4 edges per 256-thread block
    int nblocks = (N_EDGES + 3) / 4;
    scatter_kernel<<<nblocks, 256, 0, stream>>>(support, erow, ecol, eval, out, N_EDGES);
}

// Round 2
// 1243.371 us; speedup vs baseline: 8.8776x; 8.8776x over previous
//
#include <hip/hip_runtime.h>

#define N_NODES 100000
#define N_EDGES 3200000
#define DIM 256

typedef _Float16 half_t;
typedef __attribute__((ext_vector_type(4))) _Float16 half4;

// ---------------------------------------------------------------------------
// GEMM: support[M, 256] = x[M, 256] @ W[256, 256], fp32 accumulate, fp16 out.
// BM=64, BN=64, BK=16, 256 threads, 4x4 micro-tile per thread.
// ---------------------------------------------------------------------------
__global__ __launch_bounds__(256) void gemm_kernel(const float* __restrict__ A,
                                                   const float* __restrict__ B,
                                                   half_t* __restrict__ C, int M) {
    __shared__ float As[16][64 + 1];  // [k][m]
    __shared__ float Bs[16][64 + 1];  // [k][n]

    const int row0 = blockIdx.x * 64;
    const int col0 = blockIdx.y * 64;
    const int tid = threadIdx.x;
    const int tx = tid & 15;   // n-dir
    const int ty = tid >> 4;   // m-dir

    float acc[4][4] = {};

    for (int k0 = 0; k0 < DIM; k0 += 16) {
#pragma unroll
        for (int i = 0; i < 4; i++) {
            int idx = tid + i * 256;
            int r = idx >> 4, c = idx & 15;
            int gr = row0 + r;
            As[c][r] = (gr < M) ? A[(size_t)gr * DIM + k0 + c] : 0.f;
        }
#pragma unroll
        for (int i = 0; i < 4; i++) {
            int idx = tid + i * 256;
            int r = idx >> 6, c = idx & 63;
            Bs[r][c] = B[(size_t)(k0 + r) * DIM + col0 + c];
        }
        __syncthreads();

#pragma unroll
        for (int k = 0; k < 16; k++) {
            float a[4], b[4];
#pragma unroll
            for (int i = 0; i < 4; i++) a[i] = As[k][ty * 4 + i];
#pragma unroll
            for (int j = 0; j < 4; j++) b[j] = Bs[k][tx * 4 + j];
#pragma unroll
            for (int i = 0; i < 4; i++)
#pragma unroll
                for (int j = 0; j < 4; j++) acc[i][j] += a[i] * b[j];
        }
        __syncthreads();
    }

#pragma unroll
    for (int i = 0; i < 4; i++) {
        int gr = row0 + ty * 4 + i;
        if (gr < M) {
            half4 v;
            v.x = (half_t)acc[i][0]; v.y = (half_t)acc[i][1];
            v.z = (half_t)acc[i][2]; v.w = (half_t)acc[i][3];
            *(half4*)(C + (size_t)gr * DIM + col0 + tx * 4) = v;
        }
    }
}

// ---------------------------------------------------------------------------
// CSR construction: histogram -> single-block scan -> permute
// ---------------------------------------------------------------------------
__global__ __launch_bounds__(256) void hist_kernel(const int* __restrict__ erow,
                                                   int* __restrict__ counts) {
    int i = blockIdx.x * blockDim.x + threadIdx.x;
    if (i < N_EDGES) atomicAdd(&counts[erow[i]], 1);
}

// counts (in) -> offsets[N+1] (exclusive scan); also rewrites counts as cursor=offsets
__global__ __launch_bounds__(1024) void scan_kernel(int* __restrict__ counts,
                                                    int* __restrict__ offsets) {
    __shared__ int sums[1024];
    const int n = N_NODES;
    const int t = threadIdx.x;
    const int chunk = (n + 1023) / 1024;
    const int start = t * chunk;
    const int end = min(start + chunk, n);

    int local = 0;
    for (int i = start; i < end; i++) local += counts[i];
    sums[t] = local;
    __syncthreads();

    // Hillis-Steele inclusive scan over 1024 partials
    for (int off = 1; off < 1024; off <<= 1) {
        int v = (t >= off) ? sums[t - off] : 0;
        __syncthreads();
        sums[t] += v;
        __syncthreads();
    }

    int prefix = (t == 0) ? 0 : sums[t - 1];
    for (int i = start; i < end; i++) {
        int c = counts[i];
        offsets[i] = prefix;
        counts[i] = prefix;  // cursor for permute pass
        prefix += c;
    }
    if (t == 1023) offsets[n] = N_EDGES;
}

__global__ __launch_bounds__(256) void permute_kernel(const int* __restrict__ erow,
                                                      const int* __restrict__ ecol,
                                                      const float* __restrict__ eval,
                                                      int* __restrict__ cursor,
                                                      int* __restrict__ scol,
                                                      float* __restrict__ sval) {
    int i = blockIdx.x * blockDim.x + threadIdx.x;
    if (i < N_EDGES) {
        int r = erow[i];
        int p = atomicAdd(&cursor[r], 1);
        scol[p] = ecol[i];
        sval[p] = eval[i];
    }
}

// ---------------------------------------------------------------------------
// CSR SpMM: one wave per row; lane holds 4 dims (8B fp16); no atomics.
// ---------------------------------------------------------------------------
__global__ __launch_bounds__(256) void spmm_kernel(const half_t* __restrict__ support,
                                                   const int* __restrict__ offsets,
                                                   const int* __restrict__ scol,
                                                   const float* __restrict__ sval,
                                                   float* __restrict__ out) {
    int row = (blockIdx.x * blockDim.x + threadIdx.x) >> 6;
    int lane = threadIdx.x & 63;
    if (row >= N_NODES) return;

    int beg = offsets[row];
    int end = offsets[row + 1];

    float a0 = 0.f, a1 = 0.f, a2 = 0.f, a3 = 0.f;
    int e = beg;
    for (; e + 1 < end; e += 2) {
        int c0 = scol[e], c1 = scol[e + 1];
        float v0 = sval[e], v1 = sval[e + 1];
        half4 s0 = ((const half4*)(support + (size_t)c0 * DIM))[lane];
        half4 s1 = ((const half4*)(support + (size_t)c1 * DIM))[lane];
        a0 += v0 * (float)s0.x + v1 * (float)s1.x;
        a1 += v0 * (float)s0.y + v1 * (float)s1.y;
        a2 += v0 * (float)s0.z + v1 * (float)s1.z;
        a3 += v0 * (float)s0.w + v1 * (float)s1.w;
    }
    if (e < end) {
        int c = scol[e];
        float v = sval[e];
        half4 s = ((const half4*)(support + (size_t)c * DIM))[lane];
        a0 += v * (float)s.x;
        a1 += v * (float)s.y;
        a2 += v * (float)s.z;
        a3 += v * (float)s.w;
    }
    float4 o = make_float4(a0, a1, a2, a3);
    ((float4*)(out + (size_t)row * DIM))[lane] = o;
}

extern "C" void kernel_launch(void* const* d_in, const int* in_sizes, int n_in,
                              void* d_out, int out_size, void* d_ws, size_t ws_size,
                              hipStream_t stream) {
    const float* x    = (const float*)d_in[0];
    const float* w    = (const float*)d_in[1];
    const int*   erow = (const int*)d_in[2];
    const int*   ecol = (const int*)d_in[3];
    const float* eval = (const float*)d_in[4];
    float* out = (float*)d_out;

    // workspace layout (77.6 MB total; proven ws >= 102.4 MB)
    char* ws = (char*)d_ws;
    half_t* support = (half_t*)ws;                       // 51,200,000 B
    int*    counts  = (int*)(ws + 51200000);             //    400,000 B (also cursor)
    int*    offsets = (int*)(ws + 51600000);             //    400,004 B
    int*    scol    = (int*)(ws + 52000128);             // 12,800,000 B
    float*  sval    = (float*)(ws + 64800128);           // 12,800,000 B

    hipMemsetAsync(counts, 0, N_NODES * sizeof(int), stream);

    dim3 ggrid((N_NODES + 63) / 64, DIM / 64);
    gemm_kernel<<<ggrid, 256, 0, stream>>>(x, w, support, N_NODES);

    hist_kernel<<<(N_EDGES + 255) / 256, 256, 0, stream>>>(erow, counts);
    scan_kernel<<<1, 1024, 0, stream>>>(counts, offsets);
    permute_kernel<<<(N_EDGES + 255) / 256, 256, 0, stream>>>(erow, ecol, eval,
                                                              counts, scol, sval);

    // one wave per row: 100000 waves -> 25000 blocks of 256
    spmm_kernel<<<(N_NODES * 64 + 255) / 256, 256, 0, stream>>>(support, offsets,
                                                                scol, sval, out);
}

// Round 3
// 996.705 us; speedup vs baseline: 11.0746x; 1.2475x over previous
//
#include <hip/hip_runtime.h>

#define N_NODES 100000
#define N_EDGES 3200000
#define DIM 256

typedef _Float16 half_t;
typedef __attribute__((ext_vector_type(4))) _Float16 half4;
typedef __attribute__((ext_vector_type(8))) _Float16 half8;
typedef __attribute__((ext_vector_type(4))) float floatx4;

// ---------------------------------------------------------------------------
// W cast+transpose: wT[n][k] = (f16) w[k][n].  256x256, grid(8,8) x 256 thr.
// ---------------------------------------------------------------------------
__global__ __launch_bounds__(256) void castw_kernel(const float* __restrict__ w,
                                                    half_t* __restrict__ wT) {
    __shared__ float tile[32][33];
    int bk = blockIdx.x * 32;  // k block
    int bn = blockIdx.y * 32;  // n block
    int tx = threadIdx.x & 31, ty = threadIdx.x >> 5;  // 32 x 8
#pragma unroll
    for (int i = 0; i < 4; i++)
        tile[ty + i * 8][tx] = w[(size_t)(bk + ty + i * 8) * DIM + bn + tx];
    __syncthreads();
#pragma unroll
    for (int i = 0; i < 4; i++)
        wT[(size_t)(bn + ty + i * 8) * DIM + bk + tx] = (half_t)tile[tx][ty + i * 8];
}

// ---------------------------------------------------------------------------
// MFMA GEMM: support[M,256] (f16) = x[M,256] (fp32, cast in staging) @ wT^T.
// Block tile 128x128, 4 waves (each 64x64 = 4x4 MFMA 16x16x32 tiles), BK=32.
// LDS rows padded to 40 f16 (80 B = 20 banks -> 2-way aliasing, free).
// ---------------------------------------------------------------------------
#define BM 128
#define BN 128
#define BK 32
#define LDK 40

__global__ __launch_bounds__(256) void gemm_f16_kernel(const float* __restrict__ A,
                                                       const half_t* __restrict__ BT,
                                                       half_t* __restrict__ C, int M) {
    __shared__ half_t As[BM][LDK];
    __shared__ half_t Bs[BN][LDK];

    const int tid = threadIdx.x;
    const int wid = tid >> 6, lane = tid & 63;
    const int wm = wid & 1, wn = wid >> 1;
    const int row0 = blockIdx.x * BM;
    const int col0 = blockIdx.y * BN;
    const int lr = lane & 15;
    const int quad = lane >> 4;

    floatx4 acc[4][4] = {};

    // A staging map: thread -> row = tid>>1, 16 cols starting at (tid&1)*16
    const int ar = tid >> 1;
    const int ac = (tid & 1) * 16;
    const bool avalid = (row0 + ar) < M;
    const float* aptr = A + (size_t)(row0 + ar) * DIM + ac;

    for (int k0 = 0; k0 < DIM; k0 += BK) {
        // ---- stage A (fp32 -> f16): 128x32 ----
        {
            const float4* src = (const float4*)(aptr + k0);
            half_t* dst = &As[ar][ac];
#pragma unroll
            for (int i = 0; i < 4; i++) {
                float4 v = avalid ? src[i] : make_float4(0.f, 0.f, 0.f, 0.f);
                half4 h;
                h.x = (half_t)v.x; h.y = (half_t)v.y;
                h.z = (half_t)v.z; h.w = (half_t)v.w;
                ((half4*)dst)[i] = h;
            }
        }
        // ---- stage B (f16 copy): 128 n-rows x 32 k ----
        {
#pragma unroll
            for (int i = 0; i < 2; i++) {
                int ch = tid + i * 256;           // 512 chunks of 16 B
                int r = ch >> 2, cb = (ch & 3) * 8;
                half8 v = *(const half8*)(BT + (size_t)(col0 + r) * DIM + k0 + cb);
                *(half8*)&Bs[r][cb] = v;
            }
        }
        __syncthreads();

        half8 a[4], b[4];
#pragma unroll
        for (int i = 0; i < 4; i++)
            a[i] = *(const half8*)&As[wm * 64 + i * 16 + lr][quad * 8];
#pragma unroll
        for (int j = 0; j < 4; j++)
            b[j] = *(const half8*)&Bs[wn * 64 + j * 16 + lr][quad * 8];
#pragma unroll
        for (int i = 0; i < 4; i++)
#pragma unroll
            for (int j = 0; j < 4; j++)
                acc[i][j] = __builtin_amdgcn_mfma_f32_16x16x32_f16(a[i], b[j], acc[i][j], 0, 0, 0);
        __syncthreads();
    }

    // Epilogue: C/D layout col=lane&15, row=quad*4+reg
#pragma unroll
    for (int i = 0; i < 4; i++) {
#pragma unroll
        for (int j = 0; j < 4; j++) {
            int gc = col0 + wn * 64 + j * 16 + lr;
            int grb = row0 + wm * 64 + i * 16 + quad * 4;
#pragma unroll
            for (int r = 0; r < 4; r++) {
                int gr = grb + r;
                if (gr < M) C[(size_t)gr * DIM + gc] = (half_t)acc[i][j][r];
            }
        }
    }
}

// ---------------------------------------------------------------------------
// CSR construction: histogram -> single-block scan -> permute
// ---------------------------------------------------------------------------
__global__ __launch_bounds__(256) void hist_kernel(const int* __restrict__ erow,
                                                   int* __restrict__ counts) {
    int i = blockIdx.x * blockDim.x + threadIdx.x;
    if (i < N_EDGES) atomicAdd(&counts[erow[i]], 1);
}

__global__ __launch_bounds__(1024) void scan_kernel(int* __restrict__ counts,
                                                    int* __restrict__ offsets) {
    __shared__ int sums[1024];
    const int n = N_NODES;
    const int t = threadIdx.x;
    const int chunk = (n + 1023) / 1024;
    const int start = t * chunk;
    const int end = min(start + chunk, n);

    int local = 0;
    for (int i = start; i < end; i++) local += counts[i];
    sums[t] = local;
    __syncthreads();

    for (int off = 1; off < 1024; off <<= 1) {
        int v = (t >= off) ? sums[t - off] : 0;
        __syncthreads();
        sums[t] += v;
        __syncthreads();
    }

    int prefix = (t == 0) ? 0 : sums[t - 1];
    for (int i = start; i < end; i++) {
        int c = counts[i];
        offsets[i] = prefix;
        counts[i] = prefix;  // cursor for permute
        prefix += c;
    }
    if (t == 1023) offsets[n] = N_EDGES;
}

__global__ __launch_bounds__(256) void permute_kernel(const int* __restrict__ erow,
                                                      const int* __restrict__ ecol,
                                                      const float* __restrict__ eval,
                                                      int* __restrict__ cursor,
                                                      int* __restrict__ scol,
                                                      float* __restrict__ sval) {
    int i = blockIdx.x * blockDim.x + threadIdx.x;
    if (i < N_EDGES) {
        int r = erow[i];
        int p = atomicAdd(&cursor[r], 1);
        scol[p] = ecol[i];
        sval[p] = eval[i];
    }
}

// ---------------------------------------------------------------------------
// CSR SpMM: one wave per row; lane holds 4 dims (8 B f16); no atomics.
// ---------------------------------------------------------------------------
__global__ __launch_bounds__(256) void spmm_kernel(const half_t* __restrict__ support,
                                                   const int* __restrict__ offsets,
                                                   const int* __restrict__ scol,
                                                   const float* __restrict__ sval,
                                                   float* __restrict__ out) {
    int row = (blockIdx.x * blockDim.x + threadIdx.x) >> 6;
    int lane = threadIdx.x & 63;
    if (row >= N_NODES) return;

    int beg = offsets[row];
    int end = offsets[row + 1];

    float a0 = 0.f, a1 = 0.f, a2 = 0.f, a3 = 0.f;
    int e = beg;
    for (; e + 1 < end; e += 2) {
        int c0 = scol[e], c1 = scol[e + 1];
        float v0 = sval[e], v1 = sval[e + 1];
        half4 s0 = ((const half4*)(support + (size_t)c0 * DIM))[lane];
        half4 s1 = ((const half4*)(support + (size_t)c1 * DIM))[lane];
        a0 += v0 * (float)s0.x + v1 * (float)s1.x;
        a1 += v0 * (float)s0.y + v1 * (float)s1.y;
        a2 += v0 * (float)s0.z + v1 * (float)s1.z;
        a3 += v0 * (float)s0.w + v1 * (float)s1.w;
    }
    if (e < end) {
        int c = scol[e];
        float v = sval[e];
        half4 s = ((const half4*)(support + (size_t)c * DIM))[lane];
        a0 += v * (float)s.x;
        a1 += v * (float)s.y;
        a2 += v * (float)s.z;
        a3 += v * (float)s.w;
    }
    ((float4*)(out + (size_t)row * DIM))[lane] = make_float4(a0, a1, a2, a3);
}

extern "C" void kernel_launch(void* const* d_in, const int* in_sizes, int n_in,
                              void* d_out, int out_size, void* d_ws, size_t ws_size,
                              hipStream_t stream) {
    const float* x    = (const float*)d_in[0];
    const float* w    = (const float*)d_in[1];
    const int*   erow = (const int*)d_in[2];
    const int*   ecol = (const int*)d_in[3];
    const float* eval = (const float*)d_in[4];
    float* out = (float*)d_out;

    // workspace layout
    char* ws = (char*)d_ws;
    half_t* support = (half_t*)ws;                       // 51,200,000 B
    int*    counts  = (int*)(ws + 51200000);             //    400,000 B (cursor)
    int*    offsets = (int*)(ws + 51600000);             //    400,004 B
    int*    scol    = (int*)(ws + 52000128);             // 12,800,000 B
    float*  sval    = (float*)(ws + 64800128);           // 12,800,000 B
    half_t* wT      = (half_t*)(ws + 77600128);          //    131,072 B

    hipMemsetAsync(counts, 0, N_NODES * sizeof(int), stream);

    castw_kernel<<<dim3(8, 8), 256, 0, stream>>>(w, wT);

    dim3 ggrid((N_NODES + BM - 1) / BM, DIM / BN);
    gemm_f16_kernel<<<ggrid, 256, 0, stream>>>(x, wT, support, N_NODES);

    hist_kernel<<<(N_EDGES + 255) / 256, 256, 0, stream>>>(erow, counts);
    scan_kernel<<<1, 1024, 0, stream>>>(counts, offsets);
    permute_kernel<<<(N_EDGES + 255) / 256, 256, 0, stream>>>(erow, ecol, eval,
                                                              counts, scol, sval);

    spmm_kernel<<<(N_NODES * 64 + 255) / 256, 256, 0, stream>>>(support, offsets,
                                                                scol, sval, out);
}